// Round 4
// baseline (10738.112 us; speedup 1.0000x reference)
//
#include <hip/hip_runtime.h>

#define NT 2048
#define NI 128
#define NH 256
#define WPG 32
#define BPG 8

typedef unsigned long long u64;

__device__ __forceinline__ float sigm(float v) {
  return 1.0f / (1.0f + __expf(-v));
}
__device__ __forceinline__ float tanh_fast(float v) {
  v = fminf(fmaxf(v, -15.0f), 15.0f);
  float e = __expf(-2.0f * v);
  return (1.0f - e) / (1.0f + e);
}
__device__ __forceinline__ float lstm_act(float gi, float gf, float gg, float go,
                                          float& c) {
  const float ii = sigm(gi), ff = sigm(gf), gt = tanh_fast(gg), oo = sigm(go);
  c = ff * c + ii * gt;
  return oo * tanh_fast(c);
}

// relaxed agent-scope => coherent across XCDs, NO cache-maintenance ops.
__device__ __forceinline__ int ld_flag(const int* p) {
  return __hip_atomic_load(p, __ATOMIC_RELAXED, __HIP_MEMORY_SCOPE_AGENT);
}
__device__ __forceinline__ void st_flag(int* p, int v) {
  __hip_atomic_store(p, v, __ATOMIC_RELAXED, __HIP_MEMORY_SCOPE_AGENT);
}
__device__ __forceinline__ void st_h(float* p, float v) {
  __hip_atomic_store(p, v, __ATOMIC_RELAXED, __HIP_MEMORY_SCOPE_AGENT);
}
__device__ __forceinline__ u64 ld_h64(const u64* p) {
  return __hip_atomic_load(p, __ATOMIC_RELAXED, __HIP_MEMORY_SCOPE_AGENT);
}

// VALU-pipe butterfly add over the 16-lane DPP row (ks = lane&15).
template <int CTRL>
__device__ __forceinline__ float dppadd(float x) {
  int s = __builtin_amdgcn_update_dpp(0, __float_as_int(x), CTRL, 0xf, 0xf, true);
  return x + __int_as_float(s);
}
__device__ __forceinline__ float red16(float v) {
  v = dppadd<0xB1>(v);   // quad_perm [1,0,3,2] : lane ^ 1
  v = dppadd<0x4E>(v);   // quad_perm [2,3,0,1] : lane ^ 2
  v = dppadd<0x141>(v);  // row_half_mirror     : lane ^ 7
  v = dppadd<0x140>(v);  // row_mirror          : lane ^ 15
  return v;              // sum over 16-lane row; replicated in all 16
}

// 256 WGs x 512 threads, 1 WG/CU (96KB dyn LDS). Group g=bid&7: batches
// [8g,8g+8). WG j=bid>>3: units [8j,8j+8) of both layers. Thread owns ALL
// 4 gates of one unit u (w[4][24|32] in VGPRs); wave lanes = 16 k-slices x
// 2 units x 2 batch-pairs => ds_read_b128 with 32 distinct addresses (no
// broadcast waste). k-reduce = 4 DPP adds on the VALU pipe. Batch halves
// A/B pipelined; layer-skewed (phase it computes L0(it) and L1(it-1)).
__global__ __launch_bounds__(512, 1) void lstm_persistent(
    const float* __restrict__ x,
    const float* __restrict__ wih0, const float* __restrict__ whh0,
    const float* __restrict__ bih0, const float* __restrict__ bhh0,
    const float* __restrict__ wih1, const float* __restrict__ whh1,
    const float* __restrict__ bih1, const float* __restrict__ bhh1,
    const float* __restrict__ fcw, const float* __restrict__ fcb,
    float* __restrict__ out,
    float* __restrict__ h0buf, float* __restrict__ h1buf,
    int* __restrict__ flags)
{
  extern __shared__ float sm[];
  float* zz = sm;  // [4][640] = [x(128) | h0(t-1)(256) | h1(t-2)(256)] per batch

  const int tid = threadIdx.x;
  const int bid = blockIdx.x;
  const int g = bid & 7;
  const int j = bid >> 3;
  const int b0 = g * BPG;
  int* fA = flags + g * WPG;
  int* fB = flags + 256 + g * WPG;

  const bool isL0 = (tid < 256);
  const int lane = tid & 63;
  const int wv = (tid & 255) >> 6;   // wave-in-layer 0..3
  const int ks = lane & 15;          // k-slice
  const int rg2 = (lane >> 4) & 1;   // unit-in-wave
  const int bg = lane >> 5;          // batch-pair
  const int u = wv * 2 + rg2;        // unit-local 0..7
  const int col = j * 8 + u;         // hidden index

  // ---- weights + bias into registers (k = ks*4 + 64*c + e) ----
  float w[4][32];
  float bs[4];
  if (isL0) {
#pragma unroll
    for (int gt = 0; gt < 4; ++gt) {
      const int R = gt * NH + col;
      bs[gt] = bih0[R] + bhh0[R];
#pragma unroll
      for (int c = 0; c < 6; ++c)
#pragma unroll
        for (int e = 0; e < 4; ++e) {
          const int k = ks * 4 + 64 * c + e;
          w[gt][c * 4 + e] = (k < NI) ? wih0[R * NI + k] : whh0[R * NH + (k - NI)];
        }
    }
  } else {
#pragma unroll
    for (int gt = 0; gt < 4; ++gt) {
      const int R = gt * NH + col;
      bs[gt] = bih1[R] + bhh1[R];
#pragma unroll
      for (int c = 0; c < 8; ++c)
#pragma unroll
        for (int e = 0; e < 4; ++e) {
          const int k = ks * 4 + 64 * c + e;
          w[gt][c * 4 + e] = (k < NH) ? wih1[R * NH + k] : whh1[R * NH + (k - NH)];
        }
    }
  }

  float cellA0 = 0.f, cellA1 = 0.f, cellB0 = 0.f, cellB1 = 0.f;
  u64 rh0 = 0, rh1 = 0;  // staged h pieces for the upcoming phase
  float4 xv = make_float4(0.f, 0.f, 0.f, 0.f);
  if (tid < 128) {  // prologue: x for phase (A, it=0)
    xv = *reinterpret_cast<const float4*>(
        x + (size_t)(b0 + (tid >> 5)) * NT * NI + (tid & 31) * 4);
  }
  __syncthreads();

#pragma unroll 1
  for (int it = 0; it <= NT; ++it) {
#pragma unroll
    for (int half = 0; half < 2; ++half) {
      const int xb = half ? 4 : 0;
      int* fSelf = half ? fB : fA;
      int* fOther = half ? fA : fB;
      const int nit = half ? it + 1 : it;  // prefetch-target iteration
      const int oxb = half ? 0 : 4;

      // ---- 1. stage regs -> LDS ----
      if (tid < 128 && it < NT)
        *reinterpret_cast<float4*>(&zz[(tid >> 5) * 640 + (tid & 31) * 4]) = xv;
      *reinterpret_cast<u64*>(&zz[(tid >> 7) * 640 + 128 + (tid & 127) * 2]) = rh0;
      *reinterpret_cast<u64*>(&zz[(tid >> 7) * 640 + 384 + (tid & 127) * 2]) = rh1;
      __syncthreads();  // B1 (full: drains LDS writes; vm queue is empty here)

      // ---- 2. dot + DPP k-reduce + gates + publish ----
      if (isL0) {
        if (it < NT) {
          float acc[4][2] = {{0.f, 0.f}, {0.f, 0.f}, {0.f, 0.f}, {0.f, 0.f}};
          const float* z0 = &zz[(bg * 2 + 0) * 640 + ks * 4];
          const float* z1 = &zz[(bg * 2 + 1) * 640 + ks * 4];
#pragma unroll
          for (int c = 0; c < 6; ++c) {
            const float4 v0 = *reinterpret_cast<const float4*>(z0 + 64 * c);
            const float4 v1 = *reinterpret_cast<const float4*>(z1 + 64 * c);
#pragma unroll
            for (int gt = 0; gt < 4; ++gt) {
              acc[gt][0] = fmaf(w[gt][c * 4 + 0], v0.x, acc[gt][0]);
              acc[gt][0] = fmaf(w[gt][c * 4 + 1], v0.y, acc[gt][0]);
              acc[gt][0] = fmaf(w[gt][c * 4 + 2], v0.z, acc[gt][0]);
              acc[gt][0] = fmaf(w[gt][c * 4 + 3], v0.w, acc[gt][0]);
              acc[gt][1] = fmaf(w[gt][c * 4 + 0], v1.x, acc[gt][1]);
              acc[gt][1] = fmaf(w[gt][c * 4 + 1], v1.y, acc[gt][1]);
              acc[gt][1] = fmaf(w[gt][c * 4 + 2], v1.z, acc[gt][1]);
              acc[gt][1] = fmaf(w[gt][c * 4 + 3], v1.w, acc[gt][1]);
            }
          }
#pragma unroll
          for (int gt = 0; gt < 4; ++gt) {
            acc[gt][0] = red16(acc[gt][0]);
            acc[gt][1] = red16(acc[gt][1]);
          }
          float ca = half ? cellB0 : cellA0;
          const float ha = lstm_act(acc[0][0] + bs[0], acc[1][0] + bs[1],
                                    acc[2][0] + bs[2], acc[3][0] + bs[3], ca);
          if (half) cellB0 = ca; else cellA0 = ca;
          float cb = half ? cellB1 : cellA1;
          const float hb = lstm_act(acc[0][1] + bs[0], acc[1][1] + bs[1],
                                    acc[2][1] + bs[2], acc[3][1] + bs[3], cb);
          if (half) cellB1 = cb; else cellA1 = cb;
          if ((lane & 15) == 0) {
            const size_t base = (size_t)(it & 1) * 64;
            st_h(&h0buf[(base + (b0 + xb + bg * 2 + 0)) * NH + col], ha);
            st_h(&h0buf[(base + (b0 + xb + bg * 2 + 1)) * NH + col], hb);
          }
        }
      } else {
        if (it >= 1) {
          float acc[4][2] = {{0.f, 0.f}, {0.f, 0.f}, {0.f, 0.f}, {0.f, 0.f}};
          const float* z0 = &zz[(bg * 2 + 0) * 640 + 128 + ks * 4];
          const float* z1 = &zz[(bg * 2 + 1) * 640 + 128 + ks * 4];
#pragma unroll
          for (int c = 0; c < 8; ++c) {
            const float4 v0 = *reinterpret_cast<const float4*>(z0 + 64 * c);
            const float4 v1 = *reinterpret_cast<const float4*>(z1 + 64 * c);
#pragma unroll
            for (int gt = 0; gt < 4; ++gt) {
              acc[gt][0] = fmaf(w[gt][c * 4 + 0], v0.x, acc[gt][0]);
              acc[gt][0] = fmaf(w[gt][c * 4 + 1], v0.y, acc[gt][0]);
              acc[gt][0] = fmaf(w[gt][c * 4 + 2], v0.z, acc[gt][0]);
              acc[gt][0] = fmaf(w[gt][c * 4 + 3], v0.w, acc[gt][0]);
              acc[gt][1] = fmaf(w[gt][c * 4 + 0], v1.x, acc[gt][1]);
              acc[gt][1] = fmaf(w[gt][c * 4 + 1], v1.y, acc[gt][1]);
              acc[gt][1] = fmaf(w[gt][c * 4 + 2], v1.z, acc[gt][1]);
              acc[gt][1] = fmaf(w[gt][c * 4 + 3], v1.w, acc[gt][1]);
            }
          }
#pragma unroll
          for (int gt = 0; gt < 4; ++gt) {
            acc[gt][0] = red16(acc[gt][0]);
            acc[gt][1] = red16(acc[gt][1]);
          }
          float ca = half ? cellB0 : cellA0;
          const float ha = lstm_act(acc[0][0] + bs[0], acc[1][0] + bs[1],
                                    acc[2][0] + bs[2], acc[3][0] + bs[3], ca);
          if (half) cellB0 = ca; else cellA0 = ca;
          float cb = half ? cellB1 : cellA1;
          const float hb = lstm_act(acc[0][1] + bs[0], acc[1][1] + bs[1],
                                    acc[2][1] + bs[2], acc[3][1] + bs[3], cb);
          if (half) cellB1 = cb; else cellA1 = cb;
          if ((lane & 15) == 0) {
            const size_t base = (size_t)((it - 1) & 1) * 64;
            st_h(&h1buf[(base + (b0 + xb + bg * 2 + 0)) * NH + col], ha);
            st_h(&h1buf[(base + (b0 + xb + bg * 2 + 1)) * NH + col], hb);
          }
        }
      }

      // ---- 3. wait other-half flags (publish stores retire during spin) ----
      if (tid < WPG) {
        int guard = 0;
        while (ld_flag(&fOther[tid]) < nit) {
          __builtin_amdgcn_s_sleep(1);
          if (++guard > 100000000) break;
        }
      }
      __syncthreads();  // B2

      // ---- 4. prefetch next phase's h0/h1/x into regs ----
      if (nit <= NT) {
        const int p0 = (nit - 1) & 1;  // h0(nit-1) parity
        const int p1 = nit & 1;        // h1(nit-2) parity
        const int bl = tid >> 7, off = (tid & 127) * 2;
        rh0 = ld_h64(reinterpret_cast<const u64*>(
            h0buf + ((size_t)p0 * 64 + (b0 + oxb + bl)) * NH + off));
        rh1 = ld_h64(reinterpret_cast<const u64*>(
            h1buf + ((size_t)p1 * 64 + (b0 + oxb + bl)) * NH + off));
        if (tid < 128 && nit < NT) {
          xv = *reinterpret_cast<const float4*>(
              x + ((size_t)(b0 + oxb + (tid >> 5)) * NT + (size_t)nit) * NI +
              (tid & 31) * 4);
        }
      }

      // ---- 5. counted drain (publish stores retired; prefetch stays in
      //         flight) + raw barrier + flag ----
      if (nit <= NT) {
        if (tid < 128 && nit < NT)
          asm volatile("s_waitcnt vmcnt(3)" ::: "memory");
        else
          asm volatile("s_waitcnt vmcnt(2)" ::: "memory");
      } else {
        asm volatile("s_waitcnt vmcnt(0)" ::: "memory");
      }
      __builtin_amdgcn_s_barrier();  // B3 (no LDS ops since B2; vm handled above)
      if (tid == 0) st_flag(&fSelf[j], it + 1);
    }
  }

  // ---- epilogue: FC over relu(h1[T-1]) by WG j==0 of each group ----
  if (j == 0) {
    if (tid < WPG) {
      int guard = 0;
      while (ld_flag(&fA[tid]) < NT + 1 || ld_flag(&fB[tid]) < NT + 1) {
        __builtin_amdgcn_s_sleep(1);
        if (++guard > 100000000) break;
      }
    }
    __syncthreads();
    const int bb = tid >> 6, ln = tid & 63;  // 8 waves = 8 batches
    const float* hrow = h1buf + ((size_t)(((NT - 1) & 1)) * 64 + (b0 + bb)) * NH;
    const u64 u0 = ld_h64(reinterpret_cast<const u64*>(hrow + ln * 4));
    const u64 u1 = ld_h64(reinterpret_cast<const u64*>(hrow + ln * 4 + 2));
    const float ha = __uint_as_float((unsigned)u0);
    const float hb = __uint_as_float((unsigned)(u0 >> 32));
    const float hc = __uint_as_float((unsigned)u1);
    const float hd = __uint_as_float((unsigned)(u1 >> 32));
    const float4 w4 = *reinterpret_cast<const float4*>(fcw + ln * 4);
    float p = fmaxf(ha, 0.f) * w4.x + fmaxf(hb, 0.f) * w4.y +
              fmaxf(hc, 0.f) * w4.z + fmaxf(hd, 0.f) * w4.w;
#pragma unroll
    for (int off = 32; off >= 1; off >>= 1) p += __shfl_down(p, off, 64);
    if (ln == 0) out[b0 + bb] = p + fcb[0];
  }
}

extern "C" void kernel_launch(void* const* d_in, const int* in_sizes, int n_in,
                              void* d_out, int out_size, void* d_ws, size_t ws_size,
                              hipStream_t stream) {
  (void)in_sizes; (void)n_in; (void)out_size; (void)ws_size;
  const float* x    = (const float*)d_in[0];
  const float* wih0 = (const float*)d_in[1];
  const float* whh0 = (const float*)d_in[2];
  const float* bih0 = (const float*)d_in[3];
  const float* bhh0 = (const float*)d_in[4];
  const float* wih1 = (const float*)d_in[5];
  const float* whh1 = (const float*)d_in[6];
  const float* bih1 = (const float*)d_in[7];
  const float* bhh1 = (const float*)d_in[8];
  const float* fcw  = (const float*)d_in[9];
  const float* fcb  = (const float*)d_in[10];
  float* out = (float*)d_out;

  float* ws = (float*)d_ws;
  float* h0buf = ws;                        // [2][64][256] f32
  float* h1buf = ws + 2 * 64 * 256;         // [2][64][256] f32
  int* flags = (int*)(ws + 4 * 64 * 256);   // [2][8][32]

  const size_t zbytes = (size_t)(4 * 64 * 256) * sizeof(float) + 512 * sizeof(int);
  hipMemsetAsync(d_ws, 0, zbytes, stream);

  size_t shmem = 96 * 1024;  // force 1 WG/CU (co-residency, CU exclusivity)
  if (hipFuncSetAttribute(reinterpret_cast<const void*>(lstm_persistent),
                          hipFuncAttributeMaxDynamicSharedMemorySize,
                          (int)shmem) != hipSuccess) {
    shmem = 2560 * sizeof(float);  // real footprint fallback
  }

  hipLaunchKernelGGL(lstm_persistent, dim3(256), dim3(512), shmem, stream,
                     x, wih0, whh0, bih0, bhh0, wih1, whh1, bih1, bhh1,
                     fcw, fcb, out, h0buf, h1buf, flags);
}